// Round 17
// baseline (89.952 us; speedup 1.0000x reference)
//
#include <hip/hip_runtime.h>

#define NB 8192
#define OT_ELEMS (NB * 1024)   // floats of Ot, then Mt
#define EPSF 1e-10f

typedef __attribute__((ext_vector_type(4))) float f32x4;
typedef __attribute__((ext_vector_type(8))) short s16x8;   // 8 bf16 (4 VGPRs)

// Wave-local DS phase fence WITHOUT "memory" clobber (R9-R16 replay-proven).
#define SBAR() __builtin_amdgcn_sched_barrier(0)
#define LGK()  do { SBAR(); asm volatile("s_waitcnt lgkmcnt(0)"); SBAR(); } while (0)

#define MFMA_B16(A, B, C) __builtin_amdgcn_mfma_f32_16x16x32_bf16((A), (B), (C), 0, 0, 0)

// A(hi/lo) * B(hi/lo) split-precision triple product
#define PROD3(ACC, AH, AL, BH, BL)             \
  do {                                         \
    ACC = MFMA_B16((AL), (BH), ACC);           \
    ACC = MFMA_B16((AH), (BL), ACC);           \
    ACC = MFMA_B16((AH), (BH), ACC);           \
  } while (0)

// ---------------- Kernel 1: Cayley matrices M = (I-S)^-1 (I+S), stored ROW-major ----------------
__global__ void cayley_kernel(const float* __restrict__ Br,
                              const float* __restrict__ Bt,
                              const float* __restrict__ By,
                              float* __restrict__ M_out) {
  __shared__ float A[32][33];
  __shared__ float R[32][33];
  const float* B = (blockIdx.x == 0) ? Br : (blockIdx.x == 1) ? Bt : By;
  const int t = threadIdx.x;
  const int i = t >> 5, j = t & 31;
  float Lij = (j < i) ? B[i - 1 + j] : 0.0f;
  float Lji = (i < j) ? B[j - 1 + i] : 0.0f;
  float S = Lij - Lji;
  float eye = (i == j) ? 1.0f : 0.0f;
  A[i][j] = eye - S;   // I - S
  R[i][j] = eye + S;   // I + S
  __syncthreads();
  for (int p = 0; p < 32; ++p) {
    float f = A[i][p] / A[p][p];
    __syncthreads();
    if (i != p) {
      A[i][j] -= f * A[p][j];
      R[i][j] -= f * R[p][j];
    }
    __syncthreads();
  }
  // ROW-major: slot0=MR(0), slot1=MT(1024), slot2=MY(2048)
  M_out[blockIdx.x * 1024 + i * 32 + j] = R[i][j] / A[i][i];
}

// ---------------- Kernel 1b: P = MT*MR (fp32), ROW-major into ws slot 3 ----------------
__global__ void combine_kernel(float* __restrict__ ws) {
  __shared__ float sMR[1024], sMT[1024];
  const int t = threadIdx.x;
  sMR[t] = ws[t];
  sMT[t] = ws[1024 + t];
  __syncthreads();
  const int i = t >> 5, j = t & 31;
  float s = 0.f;
#pragma unroll
  for (int k = 0; k < 32; ++k)
    s = fmaf(sMT[i * 32 + k], sMR[k * 32 + j], s);
  ws[3072 + i * 32 + j] = s;   // P row-major
}

// fp32 -> bf16 hi/lo split (hi = truncated top 16 bits; lo = next 8+ mantissa bits)
__device__ __forceinline__ void cvt_hilo8(const f32x4 f0, const f32x4 f1, s16x8& hi, s16x8& lo) {
  float f[8];
#pragma unroll
  for (int e = 0; e < 4; ++e) { f[e] = f0[e]; f[4 + e] = f1[e]; }
#pragma unroll
  for (int e = 0; e < 8; ++e) {
    unsigned u = __float_as_uint(f[e]);
    hi[e] = (short)(u >> 16);
    float ah = __uint_as_float(u & 0xffff0000u);
    lo[e] = (short)(__float_as_uint(f[e] - ah) >> 16);
  }
}

__device__ __forceinline__ void read_frag_lds(const float* sb, int off, s16x8& hi, s16x8& lo) {
  f32x4 f0 = *(const f32x4*)(sb + off);
  f32x4 f1 = *(const f32x4*)(sb + off + 4);
  cvt_hilo8(f0, f1, hi, lo);
}

// ---------------- Kernel 2: one batch per wave; 5 phases / 4 fences ----------------
// Algebra: P = MT*MR. Phit = (1-at)*MT X MT^T + at*P U P^T.
// gV = MY*V'.  gS = gV + cP*(MY*Phit).  Ot = gS*MY^T  (== MY (V'+cP*Phit) MY^T).
// Mt[a] = (1-al)*m[a](L2 re-read) + al*Phit.
// P1: stage X->sb0, U->sb1, V'->sb2 (col-major)                     |F1|
// P2: B-frags X,U,V; gX=MT*X, gU=P*U, gV=MY*V' (gV stays in regs);
//     stage gX->sb3, gU->sb4 (row-major)                            |F2|
// P3: A-frags gX,gU; Phit; stage ph->sb0 COL-major (serves both uses)|F3|
// P4: issue EMA re-read; B-frags ph + rowtile ph4 (reg transpose);
//     gS = gV + cP*(MY*ph); stage gS->sb1 (row-major)               |F4|
// P5: A-frags gS; Ot = gS*MY^T; EMA blend + NT stores; Ot stored
//     DIRECTLY from C-layout (scalar NT stores) — no final round trip.
__global__ __launch_bounds__(64) void spdsru_main(
    const float* __restrict__ X, const float* __restrict__ state,
    const float* __restrict__ WR, const float* __restrict__ Wt,
    const float* __restrict__ Wphi, const float* __restrict__ Ws,
    const float* __restrict__ Mg, float* __restrict__ out) {
  __shared__ __align__(16) float sb0[1152];
  __shared__ __align__(16) float sb1[1152];
  __shared__ __align__(16) float sb2[1152];
  __shared__ __align__(16) float sb3[1152];
  __shared__ __align__(16) float sb4[1152];
  const int lane = threadIdx.x;
  const int l15 = lane & 15, l4 = lane >> 4;
  const int i0 = (lane >> 3) << 2, j0 = (lane & 7) << 2;
  // XCD-contiguous swizzle (8192 blocks)
  const int bid = blockIdx.x;
  const int batch = (bid & 7) * (NB >> 3) + (bid >> 3);

  // M fragments: q=0 -> MT (slot1), q=1 -> P (slot3), q=2 -> MY (slot2)
  s16x8 Mh[3][2], Ml[3][2];
  {
    const int srcoff[3] = {1024, 3072, 2048};
#pragma unroll
    for (int q = 0; q < 3; ++q)
#pragma unroll
      for (int s = 0; s < 2; ++s) {
        const float* p = Mg + srcoff[q] + (16 * s + l15) * 32 + 8 * l4;
        cvt_hilo8(*(const f32x4*)p, *(const f32x4*)(p + 4), Mh[q][s], Ml[q][s]);
      }
  }

  // uniform scalar weights
  const float alpha[5] = {0.01f, 0.25f, 0.5f, 0.9f, 0.99f};
  float wr[5], va[5];
  float cP = 0.f;
  {
    float sR = 0.f, sS = 0.f, wq[5];
#pragma unroll
    for (int a = 0; a < 5; ++a) { float v = WR[a]; wr[a] = v * v; sR += v * v; }
#pragma unroll
    for (int a = 0; a < 5; ++a) { float v = Ws[a]; wq[a] = v * v; sS += v * v; }
    const float invR = 1.0f / (sR + EPSF), invS = 1.0f / (sS + EPSF);
#pragma unroll
    for (int a = 0; a < 5; ++a) {
      wr[a] *= invR;
      float w = wq[a] * invS;
      va[a] = w * (1.0f - alpha[a]);
      cP += w * alpha[a];
    }
  }
  const float wt2 = Wt[0] * Wt[0], wp2 = Wphi[0] * Wphi[0];
  const float at = wt2 / (wt2 + wp2 + EPSF);
  const float omat = 1.0f - at;

  // loads: X (NT) + state pass 1 (rowtile); fold U (Yt) and V'
  const float* xp = X + (size_t)batch * 1024;
  f32x4 x[4];
#pragma unroll
  for (int r = 0; r < 4; ++r)
    x[r] = __builtin_nontemporal_load((const f32x4*)(xp + (i0 + r) * 32 + j0));

  const float* stp = state + (size_t)batch * 5120;
  f32x4 U[4], V[4];
#pragma unroll
  for (int r = 0; r < 4; ++r) { U[r] = f32x4{0.f, 0.f, 0.f, 0.f}; V[r] = U[r]; }
#pragma unroll
  for (int a = 0; a < 5; ++a)
#pragma unroll
    for (int r = 0; r < 4; ++r) {
      const f32x4 v = *(const f32x4*)(stp + a * 1024 + (i0 + r) * 32 + j0);
      U[r] += wr[a] * v;
      V[r] += va[a] * v;
    }

  // ---- P1: stage X->sb0, U->sb1, V'->sb2 (col-major, stride 36) ----
#pragma unroll
  for (int c = 0; c < 4; ++c) {
    f32x4 cx = {x[0][c], x[1][c], x[2][c], x[3][c]};
    f32x4 cu = {U[0][c], U[1][c], U[2][c], U[3][c]};
    f32x4 cv = {V[0][c], V[1][c], V[2][c], V[3][c]};
    *(f32x4*)(sb0 + (j0 + c) * 36 + i0) = cx;
    *(f32x4*)(sb1 + (j0 + c) * 36 + i0) = cu;
    *(f32x4*)(sb2 + (j0 + c) * 36 + i0) = cv;
  }
  LGK();   // F1

  // ---- P2: B-frags; gX=MT*X, gU=P*U, gV=MY*V' ; stage gX->sb3, gU->sb4 ----
  f32x4 gV[2][2];
  {
    s16x8 BXh[2], BXl[2], BUh[2], BUl[2], BVh[2], BVl[2];
#pragma unroll
    for (int s = 0; s < 2; ++s) {
      read_frag_lds(sb0, (16 * s + l15) * 36 + 8 * l4, BXh[s], BXl[s]);
      read_frag_lds(sb1, (16 * s + l15) * 36 + 8 * l4, BUh[s], BUl[s]);
      read_frag_lds(sb2, (16 * s + l15) * 36 + 8 * l4, BVh[s], BVl[s]);
    }
    f32x4 gX[2][2], gU[2][2];
#pragma unroll
    for (int ms = 0; ms < 2; ++ms)
#pragma unroll
      for (int ns = 0; ns < 2; ++ns) {
        f32x4 a0 = {0.f, 0.f, 0.f, 0.f};
        PROD3(a0, Mh[0][ms], Ml[0][ms], BXh[ns], BXl[ns]);
        gX[ms][ns] = a0;
        f32x4 a1 = {0.f, 0.f, 0.f, 0.f};
        PROD3(a1, Mh[1][ms], Ml[1][ms], BUh[ns], BUl[ns]);
        gU[ms][ns] = a1;
        f32x4 a2 = {0.f, 0.f, 0.f, 0.f};
        PROD3(a2, Mh[2][ms], Ml[2][ms], BVh[ns], BVl[ns]);
        gV[ms][ns] = a2;
      }
#pragma unroll
    for (int ms = 0; ms < 2; ++ms)
#pragma unroll
      for (int ns = 0; ns < 2; ++ns)
#pragma unroll
        for (int r = 0; r < 4; ++r) {
          sb3[(16 * ms + 4 * l4 + r) * 36 + 16 * ns + l15] = gX[ms][ns][r];
          sb4[(16 * ms + 4 * l4 + r) * 36 + 16 * ns + l15] = gU[ms][ns][r];
        }
  }
  LGK();   // F2

  // ---- P3: A-frags gX,gU; Phit = omat*(gX*MT^T) + at*(gU*P^T); stage ph->sb0 COL-major ----
  {
    s16x8 AXh[2], AXl[2], AUh[2], AUl[2];
#pragma unroll
    for (int s = 0; s < 2; ++s) {
      read_frag_lds(sb3, (16 * s + l15) * 36 + 8 * l4, AXh[s], AXl[s]);
      read_frag_lds(sb4, (16 * s + l15) * 36 + 8 * l4, AUh[s], AUl[s]);
    }
    f32x4 ph[2][2];
#pragma unroll
    for (int ms = 0; ms < 2; ++ms)
#pragma unroll
      for (int ns = 0; ns < 2; ++ns) {
        f32x4 a0 = {0.f, 0.f, 0.f, 0.f};
        PROD3(a0, AXh[ms], AXl[ms], Mh[0][ns], Ml[0][ns]);
        f32x4 a1 = {0.f, 0.f, 0.f, 0.f};
        PROD3(a1, AUh[ms], AUl[ms], Mh[1][ns], Ml[1][ns]);
        ph[ms][ns] = omat * a0 + at * a1;
      }
    // C-layout -> col-major staging is b128-friendly: 4 consecutive rows, one column
#pragma unroll
    for (int ms = 0; ms < 2; ++ms)
#pragma unroll
      for (int ns = 0; ns < 2; ++ns)
        *(f32x4*)(sb0 + (16 * ns + l15) * 36 + 16 * ms + 4 * l4) = ph[ms][ns];
  }
  LGK();   // F3

  // ---- P4: issue EMA re-read; read ph (B-frags + rowtile); gS = gV + cP*(MY*ph); stage gS->sb1 ----
  f32x4 raw2[20];
#pragma unroll
  for (int a = 0; a < 5; ++a)
#pragma unroll
    for (int r = 0; r < 4; ++r)
      raw2[a * 4 + r] = *(const f32x4*)(stp + a * 1024 + (i0 + r) * 32 + j0);
  f32x4 ph4[4];
  {
    s16x8 Bph_h[2], Bph_l[2];
#pragma unroll
    for (int s = 0; s < 2; ++s)
      read_frag_lds(sb0, (16 * s + l15) * 36 + 8 * l4, Bph_h[s], Bph_l[s]);
    // rowtile ph4 via 4 col-reads + register transpose
    f32x4 pc[4];
#pragma unroll
    for (int c = 0; c < 4; ++c)
      pc[c] = *(const f32x4*)(sb0 + (j0 + c) * 36 + i0);
#pragma unroll
    for (int r = 0; r < 4; ++r)
      ph4[r] = f32x4{pc[0][r], pc[1][r], pc[2][r], pc[3][r]};
    f32x4 gS[2][2];
#pragma unroll
    for (int ms = 0; ms < 2; ++ms)
#pragma unroll
      for (int ns = 0; ns < 2; ++ns) {
        f32x4 a2 = {0.f, 0.f, 0.f, 0.f};
        PROD3(a2, Mh[2][ms], Ml[2][ms], Bph_h[ns], Bph_l[ns]);
        gS[ms][ns] = gV[ms][ns] + cP * a2;
      }
#pragma unroll
    for (int ms = 0; ms < 2; ++ms)
#pragma unroll
      for (int ns = 0; ns < 2; ++ns)
#pragma unroll
        for (int r = 0; r < 4; ++r)
          sb1[(16 * ms + 4 * l4 + r) * 36 + 16 * ns + l15] = gS[ms][ns][r];
  }
  LGK();   // F4

  // ---- P5: A-frags gS; Ot = gS*MY^T; EMA blend + NT stores; Ot stored from C-layout ----
  {
    s16x8 ASh[2], ASl[2];
#pragma unroll
    for (int s = 0; s < 2; ++s)
      read_frag_lds(sb1, (16 * s + l15) * 36 + 8 * l4, ASh[s], ASl[s]);
    f32x4 o[2][2];
#pragma unroll
    for (int ms = 0; ms < 2; ++ms)
#pragma unroll
      for (int ns = 0; ns < 2; ++ns) {
        f32x4 acc = {0.f, 0.f, 0.f, 0.f};
        PROD3(acc, ASh[ms], ASl[ms], Mh[2][ns], Ml[2][ns]);
        o[ms][ns] = acc;
      }
    // EMA consume: Mt[a] = (1-al)*raw2 + al*Phit (rowtile dwordx4 NT stores)
    float* outMt = out + OT_ELEMS + (size_t)batch * 5120;
#pragma unroll
    for (int a = 0; a < 5; ++a) {
      const float al = alpha[a], om = 1.0f - al;
#pragma unroll
      for (int r = 0; r < 4; ++r) {
        f32x4 w = om * raw2[a * 4 + r] + al * ph4[r];
        __builtin_nontemporal_store(w, (f32x4*)(outMt + a * 1024 + (i0 + r) * 32 + j0));
      }
    }
    // Ot directly from C-layout: scalar NT stores (4x64B segments per instr)
    float* outOt = out + (size_t)batch * 1024;
#pragma unroll
    for (int ms = 0; ms < 2; ++ms)
#pragma unroll
      for (int ns = 0; ns < 2; ++ns)
#pragma unroll
        for (int r = 0; r < 4; ++r)
          __builtin_nontemporal_store(o[ms][ns][r],
              outOt + (16 * ms + 4 * l4 + r) * 32 + 16 * ns + l15);
  }
}

extern "C" void kernel_launch(void* const* d_in, const int* in_sizes, int n_in,
                              void* d_out, int out_size, void* d_ws, size_t ws_size,
                              hipStream_t stream) {
  const float* X     = (const float*)d_in[0];
  const float* state = (const float*)d_in[1];
  const float* WR    = (const float*)d_in[2];
  const float* Wt    = (const float*)d_in[3];
  const float* Wphi  = (const float*)d_in[4];
  const float* Ws    = (const float*)d_in[5];
  const float* Br    = (const float*)d_in[6];
  const float* Bt    = (const float*)d_in[7];
  const float* By    = (const float*)d_in[8];
  float* m_ws = (float*)d_ws;   // 4*1024 floats: MR, MT, MY, P (row-major)
  float* outp = (float*)d_out;

  cayley_kernel<<<3, 1024, 0, stream>>>(Br, Bt, By, m_ws);
  combine_kernel<<<1, 1024, 0, stream>>>(m_ws);
  spdsru_main<<<NB, 64, 0, stream>>>(X, state, WR, Wt, Wphi, Ws, m_ws, outp);
}